// Round 13
// baseline (3070.073 us; speedup 1.0000x reference)
//
#include <hip/hip_runtime.h>
#include <math.h>

#define NPOP 65536
#define H    2048
#define HH   1024
#define KSEL 50
#define CANDCAP 1024
#define MARGIN 0.06f

using bf16x8 = __attribute__((ext_vector_type(8))) short;
using f32x4  = __attribute__((ext_vector_type(4))) float;

__device__ __forceinline__ unsigned short f2bf(float x) {
    unsigned u = __float_as_uint(x);
    return (unsigned short)((u + 0x7FFFu + ((u >> 16) & 1u)) >> 16);
}

// ---------------- W1 transpose -> bf16 (RNE), chunk-permuted (BK=64) ----------------
// Block (0,0) additionally: zeroes hist/cnt, probes mask dtype -> mflag.
__global__ __launch_bounds__(256) void k_w1split(
    const float* __restrict__ w1, unsigned short* __restrict__ th,
    const unsigned int* __restrict__ mask, int* __restrict__ mflag,
    int* __restrict__ cnt, int* __restrict__ hist)
{
    __shared__ float tile[64][65];
    const int t = threadIdx.x;
    if (blockIdx.x == 0 && blockIdx.y == 0) {
        __shared__ int sfloat, sbyte;
        if (t == 0) { sfloat = 0; sbyte = 0; *cnt = 0; }
        for (int i = t; i < 2048; i += 256) hist[i] = 0;
        __syncthreads();
        for (int i = t; i < 25600; i += 256) {
            unsigned int v = mask[i];
            if (v == 0x3F800000u) sfloat = 1;
            else if (v & 0xFFFFFF00u) sbyte = 1;
        }
        __syncthreads();
        if (t == 0) *mflag = sfloat ? 2 : (sbyte ? 1 : 0);
    }
    const int n0 = blockIdx.x * 64;
    const int k0 = blockIdx.y * 64;
#pragma unroll
    for (int p = 0; p < 4; ++p) {
        const int kr = (t >> 4) + p * 16;
        const int nc = (t & 15) * 4;
        const float4 v = *(const float4*)&w1[(size_t)(k0 + kr) * HH + n0 + nc];
        tile[kr][nc] = v.x; tile[kr][nc + 1] = v.y; tile[kr][nc + 2] = v.z; tile[kr][nc + 3] = v.w;
    }
    __syncthreads();
#pragma unroll
    for (int p = 0; p < 4; ++p) {
        const int nr = (t >> 4) + p * 16;
        const int kc = (t & 15) * 4;
        unsigned hh[4];
#pragma unroll
        for (int e = 0; e < 4; ++e) hh[e] = f2bf(tile[kc + e][nr]);
        uint2 ph;
        ph.x = hh[0] | (hh[1] << 16); ph.y = hh[2] | (hh[3] << 16);
        const int ks = (((kc >> 3) ^ (nr & 7)) << 3) | (kc & 7);
        *(uint2*)&th[(size_t)(n0 + nr) * H + k0 + ks] = ph;
    }
}

// ---------------- fitness GEMM: 256x256, 8 waves, SINGLE 64KB buffer, 2 blocks/CU ----------------
// grid 1024 (chunked XCD swizzle), 512 thr (8 waves: 2m x 4n). BK=64.
// Per K-tile: {GLL B + PACK A + LOADA prefetch; vmcnt(8) lgkmcnt(0); barrier;
// frag reads + 64 MFMA (compiler-interleaved, setprio); barrier}. Counted vmcnt keeps
// the 8 A-prefetch loads in flight; cross-block overlap (2 blocks/CU) fills the drains.
__global__ __launch_bounds__(512, 4) void k_fit_sb(
    const float* __restrict__ pop, const unsigned short* __restrict__ w1t,
    const float* __restrict__ bias1, const float* __restrict__ w2,
    float* __restrict__ xpart)
{
    __shared__ unsigned short Ah[256 * 64];   // 32 KB
    __shared__ unsigned short Bh[256 * 64];   // 32 KB
    const int t = threadIdx.x;
    const int lane = t & 63;
    const int wid = t >> 6;             // 0..7
    const int wm = wid >> 2;            // 0..1  (128 rows each)
    const int wn = wid & 3;             // 0..3  (64 cols each)

    const int lin = (blockIdx.x & 7) * 128 + (blockIdx.x >> 3);
    const int row0 = (lin >> 2) * 256;
    const int nb = lin & 3;
    const int col0 = nb * 256;

    f32x4 acc[8][4];
#pragma unroll
    for (int i = 0; i < 8; ++i)
#pragma unroll
        for (int j = 0; j < 4; ++j) { f32x4 z = {0.f, 0.f, 0.f, 0.f}; acc[i][j] = z; }

    int aoff[8], boff[4];
#pragma unroll
    for (int i = 0; i < 8; ++i) {
        const int ra = wm * 128 + i * 16 + (lane & 15);
        aoff[i] = ra * 64 + (((lane >> 4) ^ (ra & 7)) * 8);
    }
#pragma unroll
    for (int j = 0; j < 4; ++j) {
        const int rb = wn * 64 + j * 16 + (lane & 15);
        boff[j] = rb * 64 + (((lane >> 4) ^ (rb & 7)) * 8);
    }
    int woff[4];
#pragma unroll
    for (int q = 0; q < 4; ++q) {
        const int r = (t >> 3) + 64 * q;
        woff[q] = r * 64 + (((t & 7) ^ (r & 7)) * 8);
    }
    const float* asrc = pop + (size_t)(row0 + (t >> 3)) * H + (t & 7) * 8;
    const unsigned short* bsrc = w1t + (size_t)(col0 + wid * 32 + (lane >> 3)) * H + (lane & 7) * 8;

    float4 pa[8];

#define LOADA(Q, KC2) do { \
    pa[2*(Q)]   = *(const float4*)(asrc + (size_t)(64 * (Q)) * H + (KC2)); \
    pa[2*(Q)+1] = *(const float4*)(asrc + (size_t)(64 * (Q)) * H + (KC2) + 4); \
} while (0)

#define PACKQ(Q) do { \
    uint4 wv; \
    const float4 x0 = pa[2*(Q)], x1 = pa[2*(Q)+1]; \
    wv.x = (__float_as_uint(x0.x) >> 16) | (__float_as_uint(x0.y) & 0xFFFF0000u); \
    wv.y = (__float_as_uint(x0.z) >> 16) | (__float_as_uint(x0.w) & 0xFFFF0000u); \
    wv.z = (__float_as_uint(x1.x) >> 16) | (__float_as_uint(x1.y) & 0xFFFF0000u); \
    wv.w = (__float_as_uint(x1.z) >> 16) | (__float_as_uint(x1.w) & 0xFFFF0000u); \
    *(uint4*)&Ah[woff[Q]] = wv; \
} while (0)

#define GLL4(KOFF) do { \
    _Pragma("unroll") for (int q = 0; q < 4; ++q) { \
        __builtin_amdgcn_global_load_lds( \
            (const __attribute__((address_space(1))) void*)(bsrc + (size_t)(q * 8) * H + (KOFF)), \
            (__attribute__((address_space(3))) void*)&Bh[(wid * 32 + q * 8) * 64], \
            16, 0, 0); \
    } } while (0)

    // prologue: prefetch pa <- A(0)
#pragma unroll
    for (int q = 0; q < 4; ++q) LOADA(q, 0);

    for (int k0 = 0; k0 < H; k0 += 64) {
        // stage phase: B direct-to-LDS, A pack from regs, prefetch next A
        GLL4(k0);
#pragma unroll
        for (int q = 0; q < 4; ++q) PACKQ(q);
        if (k0 + 64 < H) {
#pragma unroll
            for (int q = 0; q < 4; ++q) LOADA(q, k0 + 64);
            asm volatile("s_waitcnt vmcnt(8) lgkmcnt(0)" ::: "memory");
        } else {
            asm volatile("s_waitcnt vmcnt(0) lgkmcnt(0)" ::: "memory");
        }
        asm volatile("s_barrier" ::: "memory");
        // MFMA region: frag reads + MFMA, compiler-interleaved
        __builtin_amdgcn_s_setprio(1);
#pragma unroll
        for (int kk = 0; kk < 2; ++kk) {
            const int x = kk * 32;
            bf16x8 af[8], bf[4];
#pragma unroll
            for (int i2 = 0; i2 < 8; ++i2) af[i2] = *(const bf16x8*)&Ah[aoff[i2] ^ x];
#pragma unroll
            for (int j = 0; j < 4; ++j) bf[j] = *(const bf16x8*)&Bh[boff[j] ^ x];
#pragma unroll
            for (int i2 = 0; i2 < 8; ++i2)
#pragma unroll
                for (int j = 0; j < 4; ++j)
                    acc[i2][j] = __builtin_amdgcn_mfma_f32_16x16x32_bf16(af[i2], bf[j], acc[i2][j], 0, 0, 0);
        }
        __builtin_amdgcn_s_setprio(0);
        asm volatile("s_barrier" ::: "memory");   // reads done before next stage overwrites
    }

    // epilogue: relu + w2 dot over 4 j-frags x 16 cols -> 16 partials/row
    float part[8][4];
#pragma unroll
    for (int i = 0; i < 8; ++i)
#pragma unroll
        for (int rg = 0; rg < 4; ++rg) part[i][rg] = 0.f;
#pragma unroll
    for (int j = 0; j < 4; ++j) {
        const int col = col0 + wn * 64 + j * 16 + (lane & 15);
        const float b1c = bias1[col];
        const float w2c = w2[col];
#pragma unroll
        for (int i = 0; i < 8; ++i)
#pragma unroll
            for (int rg = 0; rg < 4; ++rg) {
                float hval = acc[i][j][rg] + b1c;
                hval = fmaxf(hval, 0.f);
                part[i][rg] = fmaf(hval, w2c, part[i][rg]);
            }
    }
#pragma unroll
    for (int m = 1; m <= 8; m <<= 1)
#pragma unroll
        for (int i = 0; i < 8; ++i)
#pragma unroll
            for (int rg = 0; rg < 4; ++rg)
                part[i][rg] += __shfl_xor(part[i][rg], m);
    if ((lane & 15) == 0) {
#pragma unroll
        for (int i = 0; i < 8; ++i)
#pragma unroll
            for (int rg = 0; rg < 4; ++rg) {
                const int row = row0 + wm * 128 + i * 16 + (lane >> 4) * 4 + rg;
                xpart[(size_t)row * 16 + nb * 4 + wn] = part[i][rg];
            }
    }
#undef LOADA
#undef PACKQ
#undef GLL4
}

// ---------------- finish: sum partials, sigmoid, raw score, histogram ----------------
__global__ void k_finishA(const float* __restrict__ xpart, const float* __restrict__ b2,
                          float* __restrict__ fit, float* __restrict__ sraw,
                          int* __restrict__ hist)
{
    const int i = blockIdx.x * 256 + threadIdx.x;
    if (i >= NPOP) return;
    float s = b2[0];
#pragma unroll
    for (int c = 0; c < 16; ++c) s += xpart[(size_t)i * 16 + c];
    sraw[i] = s;
    fit[i] = 1.f / (1.f + expf(-s));
    int b = (int)((s + 4.0f) * 256.0f);
    b = min(max(b, 0), 2047);
    atomicAdd(&hist[b], 1);
}

// ---------------- scan: hist suffix threshold, collect candidates ----------------
__global__ __launch_bounds__(256) void k_scan(const float* __restrict__ sraw,
                                              const int* __restrict__ hist,
                                              int* __restrict__ cand, int* __restrict__ cnt)
{
    __shared__ int ssuf[256];
    __shared__ float sthr;
    const int t = threadIdx.x;
    int local = 0;
#pragma unroll
    for (int j = 0; j < 8; ++j) local += hist[t * 8 + j];
    ssuf[t] = local;
    __syncthreads();
    for (int off = 1; off < 256; off <<= 1) {
        const int v = ssuf[t] + ((t + off < 256) ? ssuf[t + off] : 0);
        __syncthreads();
        ssuf[t] = v;
        __syncthreads();
    }
    if (ssuf[t] >= KSEL && (t == 255 || ssuf[t + 1] < KSEL))
        sthr = -4.0f + (float)(t * 8) * (1.0f / 256.0f) - MARGIN;
    __syncthreads();
    const float thr = sthr;
    const int i = blockIdx.x * 256 + t;
    if (sraw[i] >= thr) {
        const int p = atomicAdd(cnt, 1);
        if (p < CANDCAP) cand[p] = i;
    }
}

// ---------------- exact fp32 rescore: 4 cands/block, 1 wave per cand row ----------------
__global__ __launch_bounds__(256) void k_exact(
    const float* __restrict__ pop, const float* __restrict__ w1,
    const float* __restrict__ b1, const float* __restrict__ w2,
    const int* __restrict__ cand, const int* __restrict__ cnt,
    float* __restrict__ sex16)
{
    const int n = min(*cnt, CANDCAP);
    const int g = blockIdx.y;
    if (g * 4 >= n) return;
    __shared__ float As[4][64];
    __shared__ float Bs[64][64];
    __shared__ int rid[4];
    const int t = threadIdx.x;
    const int cc0 = blockIdx.x * 64;
    if (t < 4) rid[t] = (g * 4 + t < n) ? cand[g * 4 + t] : cand[0];
    __syncthreads();
    const int c  = t & 63;
    const int rw = t >> 6;
    float a0 = 0.f, a1 = 0.f, a2 = 0.f, a3 = 0.f;
    for (int k0 = 0; k0 < H; k0 += 64) {
        __syncthreads();
        As[rw][c] = pop[(size_t)rid[rw] * H + k0 + c];
#pragma unroll
        for (int e = 0; e < 4; ++e) {
            const int kk = (t >> 4) + e * 16;
            *(float4*)&Bs[kk][(t & 15) * 4] =
                *(const float4*)&w1[(size_t)(k0 + kk) * HH + cc0 + (t & 15) * 4];
        }
        __syncthreads();
#pragma unroll
        for (int kk = 0; kk < 64; kk += 4) {
            a0 = fmaf(As[rw][kk + 0], Bs[kk + 0][c], a0);
            a1 = fmaf(As[rw][kk + 1], Bs[kk + 1][c], a1);
            a2 = fmaf(As[rw][kk + 2], Bs[kk + 2][c], a2);
            a3 = fmaf(As[rw][kk + 3], Bs[kk + 3][c], a3);
        }
    }
    const float acc = (a0 + a1) + (a2 + a3);
    float h = fmaxf(acc + b1[cc0 + c], 0.f);
    float p = h * w2[cc0 + c];
#pragma unroll
    for (int s = 32; s >= 1; s >>= 1) p += __shfl_xor(p, s);
    if (c == 0 && g * 4 + rw < n)
        sex16[(size_t)(g * 4 + rw) * 16 + blockIdx.x] = p;
}

// ---------------- final exact top-50: rank-by-counting, single pass ----------------
__global__ __launch_bounds__(1024) void k_final(
    const float* __restrict__ sex16, const int* __restrict__ cand,
    const int* __restrict__ cnt, int* __restrict__ best)
{
    __shared__ unsigned long long skey[1024];
    const int t = threadIdx.x;
    const int n = min(*cnt, CANDCAP);
    unsigned long long key = 0ull;
    if (t < n) {
        float s = 0.f;
#pragma unroll
        for (int c = 0; c < 16; ++c) s += sex16[(size_t)t * 16 + c];
        unsigned u = __float_as_uint(s);
        u = ((int)u < 0) ? ~u : (u | 0x80000000u);
        key = ((unsigned long long)u << 32) | (unsigned)(~(unsigned)cand[t]);
    }
    skey[t] = key;
    __syncthreads();
    if (t < n) {
        int rank = 0;
        for (int j = 0; j < n; ++j) rank += (skey[j] > key) ? 1 : 0;
        if (rank < KSEL) best[rank] = cand[t];
    }
}

// ---------------- mutation partial GEMM (split-K x16, optional row indirection) ----------------
__global__ __launch_bounds__(256) void k_mutp(
    const float* __restrict__ A, const int* __restrict__ bidx,
    const float* __restrict__ W, float* __restrict__ part)
{
    __shared__ float As[KSEL][32];
    __shared__ float Bs[32][64];
    __shared__ int sidx[KSEL];
    const int t = threadIdx.x;
    if (t < KSEL) sidx[t] = bidx ? bidx[t] : t;
    __syncthreads();
    const int col0 = blockIdx.x * 64;
    const int kbeg = blockIdx.y * 128;
    const int c = t & 63;
    const int rg = t >> 6;
    float acc[13];
#pragma unroll
    for (int m = 0; m < 13; ++m) acc[m] = 0.f;

    for (int k0 = kbeg; k0 < kbeg + 128; k0 += 32) {
        __syncthreads();
        for (int e = t; e < KSEL * 8; e += 256) {
            const int r = e >> 3, kc = (e & 7) << 2;
            *(float4*)&As[r][kc] = *(const float4*)&A[(size_t)sidx[r] * H + k0 + kc];
        }
        for (int e = t; e < 32 * 16; e += 256) {
            const int kk = e >> 4, cc = (e & 15) << 2;
            *(float4*)&Bs[kk][cc] = *(const float4*)&W[(size_t)(k0 + kk) * H + col0 + cc];
        }
        __syncthreads();
#pragma unroll
        for (int k4 = 0; k4 < 8; ++k4) {
            const float bv0 = Bs[k4 * 4 + 0][c];
            const float bv1 = Bs[k4 * 4 + 1][c];
            const float bv2 = Bs[k4 * 4 + 2][c];
            const float bv3 = Bs[k4 * 4 + 3][c];
#pragma unroll
            for (int m = 0; m < 13; ++m) {
                const int r = rg + m * 4;
                if (r < KSEL) {
                    const float4 av = *(const float4*)&As[r][k4 * 4];
                    acc[m] = fmaf(av.x, bv0, acc[m]);
                    acc[m] = fmaf(av.y, bv1, acc[m]);
                    acc[m] = fmaf(av.z, bv2, acc[m]);
                    acc[m] = fmaf(av.w, bv3, acc[m]);
                }
            }
        }
    }
#pragma unroll
    for (int m = 0; m < 13; ++m) {
        const int r = rg + m * 4;
        if (r < KSEL)
            part[((size_t)blockIdx.y * KSEL + r) * H + col0 + c] = acc[m];
    }
}

__global__ void k_mut1c(const float* __restrict__ part, const float* __restrict__ b,
                        float* __restrict__ mid)
{
    const int i = blockIdx.x * 256 + threadIdx.x;
    if (i >= KSEL * H) return;
    const int c = i & 2047;
    float s = 0.f;
#pragma unroll
    for (int p = 0; p < 16; ++p) s += part[i + (size_t)p * KSEL * H];
    const float v = s + b[c];
    mid[i] = 0.5f * v * (1.f + erff(v * 0.70710678118654752f));
}

__global__ void k_mut2c(const float* __restrict__ part, const float* __restrict__ b,
                        const float* __restrict__ pop, const int* __restrict__ best,
                        const void* __restrict__ mask,
                        const int* __restrict__ mflag, float* __restrict__ out)
{
    const int i = blockIdx.x * 256 + threadIdx.x;
    if (i >= KSEL * H) return;
    const int c = i & 2047;
    const int r = i >> 11;
    float s = 0.f;
#pragma unroll
    for (int p = 0; p < 16; ++p) s += part[i + (size_t)p * KSEL * H];
    const float v = s + b[c];
    const int mf = *mflag;
    bool mv;
    if (mf == 2)      mv = ((const float*)mask)[i] != 0.f;
    else if (mf == 1) mv = ((const unsigned char*)mask)[i] != 0;
    else              mv = ((const int*)mask)[i] != 0;
    out[i] = mv ? pop[(size_t)best[r] * H + c] : v;
}

// ================= fallback (round-1 proven) path =================
__global__ void k_maskdetect(const unsigned int* __restrict__ m, int* __restrict__ flag,
                             int* __restrict__ cnt, int* __restrict__ hist) {
    __shared__ int sfloat, sbyte;
    if (threadIdx.x == 0) { sfloat = 0; sbyte = 0; *cnt = 0; }
    for (int i = threadIdx.x; i < 2048; i += 256) hist[i] = 0;
    __syncthreads();
    for (int i = threadIdx.x; i < 25600; i += 256) {
        unsigned int v = m[i];
        if (v == 0x3F800000u) sfloat = 1;
        else if (v & 0xFFFFFF00u) sbyte = 1;
    }
    __syncthreads();
    if (threadIdx.x == 0) *flag = sfloat ? 2 : (sbyte ? 1 : 0);
}

__global__ __launch_bounds__(256) void k_fit_gemm(
    const float* __restrict__ pop, const float* __restrict__ w1,
    const float* __restrict__ bias1, const float* __restrict__ w2,
    float* __restrict__ xpart)
{
    __shared__ float As[16][128];
    __shared__ float Bs[16][128];
    const int nb   = blockIdx.x;
    const int row0 = blockIdx.y * 128;
    const int col0 = nb * 128;
    const int t  = threadIdx.x;
    const int tx = t & 15;
    const int ty = t >> 4;
    float acc[8][8];
#pragma unroll
    for (int i = 0; i < 8; ++i)
#pragma unroll
        for (int j = 0; j < 8; ++j) acc[i][j] = 0.f;
    const int lr = t >> 1;
    const int lk = (t & 1) * 8;
    const int bk = t >> 4;
    const int bc = (t & 15) * 8;
    for (int k0 = 0; k0 < H; k0 += 16) {
        const float4 a0 = *(const float4*)(pop + (size_t)(row0 + lr) * H + k0 + lk);
        const float4 a1 = *(const float4*)(pop + (size_t)(row0 + lr) * H + k0 + lk + 4);
        const float4 c0 = *(const float4*)(w1 + (size_t)(k0 + bk) * HH + col0 + bc);
        const float4 c1 = *(const float4*)(w1 + (size_t)(k0 + bk) * HH + col0 + bc + 4);
        __syncthreads();
        As[lk + 0][lr] = a0.x; As[lk + 1][lr] = a0.y; As[lk + 2][lr] = a0.z; As[lk + 3][lr] = a0.w;
        As[lk + 4][lr] = a1.x; As[lk + 5][lr] = a1.y; As[lk + 6][lr] = a1.z; As[lk + 7][lr] = a1.w;
        *(float4*)&Bs[bk][bc]     = c0;
        *(float4*)&Bs[bk][bc + 4] = c1;
        __syncthreads();
#pragma unroll
        for (int kk = 0; kk < 16; ++kk) {
            const float4 ra0 = *(const float4*)&As[kk][ty * 8];
            const float4 ra1 = *(const float4*)&As[kk][ty * 8 + 4];
            const float4 rb0 = *(const float4*)&Bs[kk][tx * 8];
            const float4 rb1 = *(const float4*)&Bs[kk][tx * 8 + 4];
            const float av[8] = {ra0.x, ra0.y, ra0.z, ra0.w, ra1.x, ra1.y, ra1.z, ra1.w};
            const float bv[8] = {rb0.x, rb0.y, rb0.z, rb0.w, rb1.x, rb1.y, rb1.z, rb1.w};
#pragma unroll
            for (int i = 0; i < 8; ++i)
#pragma unroll
                for (int j = 0; j < 8; ++j)
                    acc[i][j] = fmaf(av[i], bv[j], acc[i][j]);
        }
    }
    float part[8];
#pragma unroll
    for (int i = 0; i < 8; ++i) part[i] = 0.f;
#pragma unroll
    for (int j = 0; j < 8; ++j) {
        const int c = col0 + tx * 8 + j;
        const float bb = bias1[c];
        const float ww = w2[c];
#pragma unroll
        for (int i = 0; i < 8; ++i) {
            float hh = acc[i][j] + bb;
            hh = fmaxf(hh, 0.f);
            part[i] = fmaf(hh, ww, part[i]);
        }
    }
#pragma unroll
    for (int m = 1; m <= 8; m <<= 1)
#pragma unroll
        for (int i = 0; i < 8; ++i) part[i] += __shfl_xor(part[i], m);
    if (tx == 0) {
#pragma unroll
        for (int i = 0; i < 8; ++i)
            xpart[(size_t)(row0 + ty * 8 + i) * 8 + nb] = part[i];
    }
}

__global__ void k_fit_finish8(const float* __restrict__ xpart,
                              const float* __restrict__ b2, float* __restrict__ fit)
{
    const int i = blockIdx.x * 256 + threadIdx.x;
    if (i >= NPOP) return;
    float s = b2[0];
#pragma unroll
    for (int nb = 0; nb < 8; ++nb) s += xpart[(size_t)i * 8 + nb];
    fit[i] = 1.f / (1.f + expf(-s));
}

__global__ __launch_bounds__(1024) void k_topk3(const float* __restrict__ fit,
                                                int* __restrict__ best)
{
    __shared__ unsigned long long skey[1024];
    __shared__ unsigned long long wred[16];
    __shared__ unsigned int taken[NPOP / 32];
    __shared__ int brd;
    const int t = threadIdx.x;
    for (int i = t; i < NPOP / 32; i += 1024) taken[i] = 0u;
    unsigned long long k = 0ull;
#pragma unroll 4
    for (int i = 0; i < 64; ++i) {
        const int idx = t + (i << 10);
        const unsigned fv = __float_as_uint(fit[idx]);
        const unsigned long long key = ((unsigned long long)fv << 32) | (unsigned)(~(unsigned)idx);
        if (key > k) k = key;
    }
    skey[t] = k;
    __syncthreads();
    for (int r = 0; r < KSEL; ++r) {
        unsigned long long v = skey[t];
#pragma unroll
        for (int m = 32; m >= 1; m >>= 1) {
            const unsigned long long o = __shfl_xor(v, m);
            if (o > v) v = o;
        }
        if ((t & 63) == 0) wred[t >> 6] = v;
        __syncthreads();
        if (t == 0) {
            unsigned long long b = wred[0];
#pragma unroll
            for (int w = 1; w < 16; ++w) if (wred[w] > b) b = wred[w];
            const int idx = (int)(~(unsigned)(b & 0xFFFFFFFFull));
            best[r] = idx;
            taken[idx >> 5] |= (1u << (idx & 31));
            brd = idx;
        }
        __syncthreads();
        if (r + 1 < KSEL) {
            const int s = brd & 1023;
            if (t < 64) {
                const int e = s + (t << 10);
                unsigned long long k2 = 0ull;
                if (!(taken[e >> 5] & (1u << (e & 31)))) {
                    const unsigned fv = __float_as_uint(fit[e]);
                    k2 = ((unsigned long long)fv << 32) | (unsigned)(~(unsigned)e);
                }
#pragma unroll
                for (int m = 32; m >= 1; m >>= 1) {
                    const unsigned long long o = __shfl_xor(k2, m);
                    if (o > k2) k2 = o;
                }
                if (t == 0) skey[s] = k2;
            }
            __syncthreads();
        }
    }
}

__global__ __launch_bounds__(256) void k_mut1(
    const float* __restrict__ pop, const int* __restrict__ best,
    const float* __restrict__ w, const float* __restrict__ b, float* __restrict__ mid)
{
    __shared__ float As[KSEL][32];
    __shared__ float Bs[32][64];
    __shared__ int sidx[KSEL];
    const int t = threadIdx.x;
    if (t < KSEL) sidx[t] = best[t];
    __syncthreads();
    const int col0 = blockIdx.x * 64;
    const int c  = t & 63;
    const int rg = t >> 6;
    float acc[13];
#pragma unroll
    for (int m = 0; m < 13; ++m) acc[m] = 0.f;
    for (int k0 = 0; k0 < H; k0 += 32) {
        __syncthreads();
        for (int e = t; e < KSEL * 32; e += 256) {
            const int r = e >> 5, kk = e & 31;
            As[r][kk] = pop[(size_t)sidx[r] * H + k0 + kk];
        }
        for (int e = t; e < 32 * 64; e += 256) {
            const int kk = e >> 6, cc = e & 63;
            Bs[kk][cc] = w[(size_t)(k0 + kk) * H + col0 + cc];
        }
        __syncthreads();
#pragma unroll
        for (int k4 = 0; k4 < 8; ++k4) {
            const float bv0 = Bs[k4 * 4 + 0][c];
            const float bv1 = Bs[k4 * 4 + 1][c];
            const float bv2 = Bs[k4 * 4 + 2][c];
            const float bv3 = Bs[k4 * 4 + 3][c];
#pragma unroll
            for (int m = 0; m < 13; ++m) {
                const int r = rg + m * 4;
                if (r < KSEL) {
                    const float4 av = *(const float4*)&As[r][k4 * 4];
                    acc[m] = fmaf(av.x, bv0, acc[m]);
                    acc[m] = fmaf(av.y, bv1, acc[m]);
                    acc[m] = fmaf(av.z, bv2, acc[m]);
                    acc[m] = fmaf(av.w, bv3, acc[m]);
                }
            }
        }
    }
#pragma unroll
    for (int m = 0; m < 13; ++m) {
        const int r = rg + m * 4;
        if (r < KSEL) {
            const int col = col0 + c;
            const float v = acc[m] + b[col];
            mid[(size_t)r * H + col] = 0.5f * v * (1.f + erff(v * 0.70710678118654752f));
        }
    }
}

__global__ __launch_bounds__(256) void k_mut2(
    const float* __restrict__ mid, const float* __restrict__ w,
    const float* __restrict__ b, const float* __restrict__ pop,
    const int* __restrict__ best, const void* __restrict__ mask,
    const int* __restrict__ mflag, float* __restrict__ out)
{
    __shared__ float As[KSEL][32];
    __shared__ float Bs[32][64];
    __shared__ int sidx[KSEL];
    const int t = threadIdx.x;
    if (t < KSEL) sidx[t] = best[t];
    __syncthreads();
    const int col0 = blockIdx.x * 64;
    const int c  = t & 63;
    const int rg = t >> 6;
    const int mf = *mflag;
    float acc[13];
#pragma unroll
    for (int m = 0; m < 13; ++m) acc[m] = 0.f;
    for (int k0 = 0; k0 < H; k0 += 32) {
        __syncthreads();
        for (int e = t; e < KSEL * 32; e += 256) {
            const int r = e >> 5, kk = e & 31;
            As[r][kk] = mid[(size_t)r * H + k0 + kk];
        }
        for (int e = t; e < 32 * 64; e += 256) {
            const int kk = e >> 6, cc = e & 63;
            Bs[kk][cc] = w[(size_t)(k0 + kk) * H + col0 + cc];
        }
        __syncthreads();
#pragma unroll
        for (int k4 = 0; k4 < 8; ++k4) {
            const float bv0 = Bs[k4 * 4 + 0][c];
            const float bv1 = Bs[k4 * 4 + 1][c];
            const float bv2 = Bs[k4 * 4 + 2][c];
            const float bv3 = Bs[k4 * 4 + 3][c];
#pragma unroll
            for (int m = 0; m < 13; ++m) {
                const int r = rg + m * 4;
                if (r < KSEL) {
                    const float4 av = *(const float4*)&As[r][k4 * 4];
                    acc[m] = fmaf(av.x, bv0, acc[m]);
                    acc[m] = fmaf(av.y, bv1, acc[m]);
                    acc[m] = fmaf(av.z, bv2, acc[m]);
                    acc[m] = fmaf(av.w, bv3, acc[m]);
                }
            }
        }
    }
#pragma unroll
    for (int m = 0; m < 13; ++m) {
        const int r = rg + m * 4;
        if (r < KSEL) {
            const int col = col0 + c;
            const size_t mi = (size_t)r * H + col;
            const float v = acc[m] + b[col];
            bool mv;
            if (mf == 2)      mv = ((const float*)mask)[mi] != 0.f;
            else if (mf == 1) mv = ((const unsigned char*)mask)[mi] != 0;
            else              mv = ((const int*)mask)[mi] != 0;
            out[mi] = mv ? pop[(size_t)sidx[r] * H + col] : v;
        }
    }
}

// ================= launcher =================
extern "C" void kernel_launch(void* const* d_in, const int* in_sizes, int n_in,
                              void* d_out, int out_size, void* d_ws, size_t ws_size,
                              hipStream_t stream) {
    const float* pop = (const float*)d_in[0];
    const float* sw1 = (const float*)d_in[1];
    const float* sb1 = (const float*)d_in[2];
    const float* sw2 = (const float*)d_in[3];
    const float* sb2 = (const float*)d_in[4];
    const float* mw1 = (const float*)d_in[5];
    const float* mb1 = (const float*)d_in[6];
    const float* mw2 = (const float*)d_in[7];
    const float* mb2 = (const float*)d_in[8];
    const void*  mask = d_in[9];

    float* out_off = (float*)d_out;
    float* out_fit = (float*)d_out + (size_t)KSEL * H;

    char* ws = (char*)d_ws;

    // fast-path ws layout (bytes)
    const size_t W1T_OFF   = 0;            // 4,194,304
    const size_t XPART_OFF = 4194304;      // 65536*16*4 = 4,194,304
    const size_t SRAW_OFF  = 8388608;      // 262,144
    const size_t HIST_OFF  = 8650752;      // 8,192
    const size_t PPART_OFF = 8658944;      // 16*50*2048*4 = 6,553,600
    const size_t MID_OFF   = 15212544;     // 409,600
    const size_t CAND_OFF  = 15622144;     // 4,096
    const size_t SEX_OFF   = 15626240;     // 65,536
    const size_t BEST_OFF  = 15691776;     // 256
    const size_t MFLAG_OFF = 15692032;     // 128
    const size_t CNT_OFF   = 15692160;     // 128
    const size_t NEED      = 15692288;

    if (ws_size >= NEED) {
        unsigned short* w1t  = (unsigned short*)(ws + W1T_OFF);
        float* xpart = (float*)(ws + XPART_OFF);
        float* sraw  = (float*)(ws + SRAW_OFF);
        int*   hist  = (int*)(ws + HIST_OFF);
        float* ppart = (float*)(ws + PPART_OFF);
        float* mid   = (float*)(ws + MID_OFF);
        int*   cand  = (int*)(ws + CAND_OFF);
        float* sex16 = (float*)(ws + SEX_OFF);
        int*   best  = (int*)(ws + BEST_OFF);
        int*   mflag = (int*)(ws + MFLAG_OFF);
        int*   cnt   = (int*)(ws + CNT_OFF);

        hipLaunchKernelGGL(k_w1split, dim3(16, 32), dim3(256), 0, stream,
                           sw1, w1t, (const unsigned int*)mask, mflag, cnt, hist);
        hipLaunchKernelGGL(k_fit_sb, dim3(1024), dim3(512), 0, stream,
                           pop, w1t, sb1, sw2, xpart);
        hipLaunchKernelGGL(k_finishA, dim3(NPOP / 256), dim3(256), 0, stream,
                           xpart, sb2, out_fit, sraw, hist);
        hipLaunchKernelGGL(k_scan, dim3(NPOP / 256), dim3(256), 0, stream,
                           sraw, hist, cand, cnt);
        hipLaunchKernelGGL(k_exact, dim3(16, 256), dim3(256), 0, stream,
                           pop, sw1, sb1, sw2, cand, cnt, sex16);
        hipLaunchKernelGGL(k_final, dim3(1), dim3(1024), 0, stream,
                           sex16, cand, cnt, best);
        hipLaunchKernelGGL(k_mutp, dim3(32, 16), dim3(256), 0, stream,
                           pop, best, mw1, ppart);
        hipLaunchKernelGGL(k_mut1c, dim3(KSEL * H / 256), dim3(256), 0, stream,
                           ppart, mb1, mid);
        hipLaunchKernelGGL(k_mutp, dim3(32, 16), dim3(256), 0, stream,
                           mid, (const int*)nullptr, mw2, ppart);
        hipLaunchKernelGGL(k_mut2c, dim3(KSEL * H / 256), dim3(256), 0, stream,
                           ppart, mb2, pop, best, mask, mflag, out_off);
    } else {
        // fallback: round-1 proven path (exact fp32 fitness)
        float* xpart = (float*)ws;
        int*   best  = (int*)(ws + (size_t)NPOP * 8 * 4);
        int*   mflag = (int*)(ws + (size_t)NPOP * 8 * 4 + 256);
        int*   cnt   = (int*)(ws + (size_t)NPOP * 8 * 4 + 384);
        int*   hist  = (int*)(ws + (size_t)NPOP * 8 * 4 + 512);
        float* mid   = (float*)(ws + (size_t)NPOP * 8 * 4 + 8704);

        hipLaunchKernelGGL(k_maskdetect, dim3(1), dim3(256), 0, stream,
                           (const unsigned int*)mask, mflag, cnt, hist);
        hipLaunchKernelGGL(k_fit_gemm, dim3(8, 512), dim3(256), 0, stream,
                           pop, sw1, sb1, sw2, xpart);
        hipLaunchKernelGGL(k_fit_finish8, dim3(NPOP / 256), dim3(256), 0, stream,
                           xpart, sb2, out_fit);
        hipLaunchKernelGGL(k_topk3, dim3(1), dim3(1024), 0, stream, out_fit, best);
        hipLaunchKernelGGL(k_mut1, dim3(H / 64), dim3(256), 0, stream,
                           pop, best, mw1, mb1, mid);
        hipLaunchKernelGGL(k_mut2, dim3(H / 64), dim3(256), 0, stream,
                           mid, mw2, mb2, pop, best, mask, mflag, out_off);
    }
}

// Round 14
// 508.122 us; speedup vs baseline: 6.0420x; 6.0420x over previous
//
#include <hip/hip_runtime.h>
#include <math.h>

#define NPOP 65536
#define H    2048
#define HH   1024
#define KSEL 50
#define CANDCAP 1024
#define MARGIN 0.06f

using bf16x8 = __attribute__((ext_vector_type(8))) short;
using f32x4  = __attribute__((ext_vector_type(4))) float;

__device__ __forceinline__ unsigned short f2bf(float x) {
    unsigned u = __float_as_uint(x);
    return (unsigned short)((u + 0x7FFFu + ((u >> 16) & 1u)) >> 16);
}

// ---------------- W1 transpose -> bf16 (RNE), chunk-permuted (BK=64) ----------------
// Block (0,0) additionally: zeroes hist/cnt, probes mask dtype -> mflag.
__global__ __launch_bounds__(256) void k_w1split(
    const float* __restrict__ w1, unsigned short* __restrict__ th,
    const unsigned int* __restrict__ mask, int* __restrict__ mflag,
    int* __restrict__ cnt, int* __restrict__ hist)
{
    __shared__ float tile[64][65];
    const int t = threadIdx.x;
    if (blockIdx.x == 0 && blockIdx.y == 0) {
        __shared__ int sfloat, sbyte;
        if (t == 0) { sfloat = 0; sbyte = 0; *cnt = 0; }
        for (int i = t; i < 2048; i += 256) hist[i] = 0;
        __syncthreads();
        for (int i = t; i < 25600; i += 256) {
            unsigned int v = mask[i];
            if (v == 0x3F800000u) sfloat = 1;
            else if (v & 0xFFFFFF00u) sbyte = 1;
        }
        __syncthreads();
        if (t == 0) *mflag = sfloat ? 2 : (sbyte ? 1 : 0);
    }
    const int n0 = blockIdx.x * 64;
    const int k0 = blockIdx.y * 64;
#pragma unroll
    for (int p = 0; p < 4; ++p) {
        const int kr = (t >> 4) + p * 16;
        const int nc = (t & 15) * 4;
        const float4 v = *(const float4*)&w1[(size_t)(k0 + kr) * HH + n0 + nc];
        tile[kr][nc] = v.x; tile[kr][nc + 1] = v.y; tile[kr][nc + 2] = v.z; tile[kr][nc + 3] = v.w;
    }
    __syncthreads();
#pragma unroll
    for (int p = 0; p < 4; ++p) {
        const int nr = (t >> 4) + p * 16;
        const int kc = (t & 15) * 4;
        unsigned hh[4];
#pragma unroll
        for (int e = 0; e < 4; ++e) hh[e] = f2bf(tile[kc + e][nr]);
        uint2 ph;
        ph.x = hh[0] | (hh[1] << 16); ph.y = hh[2] | (hh[3] << 16);
        const int ks = (((kc >> 3) ^ (nr & 7)) << 3) | (kc & 7);
        *(uint2*)&th[(size_t)(n0 + nr) * H + k0 + ks] = ph;
    }
}

// ---------------- fitness GEMM: 256x256 tile, 8 waves, 4-phase/K-tile, counted vmcnt ----------------
// grid 1024 (chunked XCD swizzle, 1024%8==0 bijective), 512 thr (8 waves: 2m x 4n).
// BK=64, double-buffered 128 KB LDS. Per phase: stage-share + frag reads, raw s_barrier,
// setprio(1) + 16 MFMA + setprio(0), raw s_barrier. One vmcnt(8) per K-tile keeps the
// 8 A-prefetch loads in flight across the tile boundary (T3+T4+T5).
__global__ __launch_bounds__(512, 2) void k_fit_8ph(
    const float* __restrict__ pop, const unsigned short* __restrict__ w1t,
    const float* __restrict__ bias1, const float* __restrict__ w2,
    float* __restrict__ xpart)
{
    __shared__ unsigned short Ah[2][256 * 64];
    __shared__ unsigned short Bh[2][256 * 64];
    const int t = threadIdx.x;
    const int lane = t & 63;
    const int wid = t >> 6;             // 0..7
    const int wm = wid >> 2;            // 0..1  (128 rows each)
    const int wn = wid & 3;             // 0..3  (64 cols each)

    const int lin = (blockIdx.x & 7) * 128 + (blockIdx.x >> 3);
    const int row0 = (lin >> 2) * 256;
    const int nb = lin & 3;
    const int col0 = nb * 256;

    f32x4 acc[8][4];
#pragma unroll
    for (int i = 0; i < 8; ++i)
#pragma unroll
        for (int j = 0; j < 4; ++j) { f32x4 z = {0.f, 0.f, 0.f, 0.f}; acc[i][j] = z; }

    int aoff[8], boff[4];
#pragma unroll
    for (int i = 0; i < 8; ++i) {
        const int ra = wm * 128 + i * 16 + (lane & 15);
        aoff[i] = ra * 64 + (((lane >> 4) ^ (ra & 7)) * 8);
    }
#pragma unroll
    for (int j = 0; j < 4; ++j) {
        const int rb = wn * 64 + j * 16 + (lane & 15);
        boff[j] = rb * 64 + (((lane >> 4) ^ (rb & 7)) * 8);
    }
    int woff[4];
#pragma unroll
    for (int q = 0; q < 4; ++q) {
        const int r = (t >> 3) + 64 * q;
        woff[q] = r * 64 + (((t & 7) ^ (r & 7)) * 8);
    }
    const float* asrc = pop + (size_t)(row0 + (t >> 3)) * H + (t & 7) * 8;
    const unsigned short* bsrc = w1t + (size_t)(col0 + wid * 32 + (lane >> 3)) * H + (lane & 7) * 8;

    float4 pa[8];

#define LOADA(Q, KC2) do { \
    pa[2*(Q)]   = *(const float4*)(asrc + (size_t)(64 * (Q)) * H + (KC2)); \
    pa[2*(Q)+1] = *(const float4*)(asrc + (size_t)(64 * (Q)) * H + (KC2) + 4); \
} while (0)

#define PACKQ(BUF, Q) do { \
    uint4 wv; \
    const float4 x0 = pa[2*(Q)], x1 = pa[2*(Q)+1]; \
    wv.x = (__float_as_uint(x0.x) >> 16) | (__float_as_uint(x0.y) & 0xFFFF0000u); \
    wv.y = (__float_as_uint(x0.z) >> 16) | (__float_as_uint(x0.w) & 0xFFFF0000u); \
    wv.z = (__float_as_uint(x1.x) >> 16) | (__float_as_uint(x1.y) & 0xFFFF0000u); \
    wv.w = (__float_as_uint(x1.z) >> 16) | (__float_as_uint(x1.w) & 0xFFFF0000u); \
    *(uint4*)&Ah[BUF][woff[Q]] = wv; \
} while (0)

#define GLL4(BUF, KOFF) do { \
    _Pragma("unroll") for (int q = 0; q < 4; ++q) { \
        __builtin_amdgcn_global_load_lds( \
            (const __attribute__((address_space(1))) void*)(bsrc + (size_t)(q * 8) * H + (KOFF)), \
            (__attribute__((address_space(3))) void*)&Bh[BUF][(wid * 32 + q * 8) * 64], \
            16, 0, 0); \
    } } while (0)

#define MPHASE(CUR, IH, KK) do { \
    bf16x8 af[4], bf[4]; \
    _Pragma("unroll") for (int i2 = 0; i2 < 4; ++i2) \
        af[i2] = *(const bf16x8*)&Ah[CUR][aoff[(IH)*4 + i2] ^ ((KK)*32)]; \
    _Pragma("unroll") for (int j = 0; j < 4; ++j) \
        bf[j] = *(const bf16x8*)&Bh[CUR][boff[j] ^ ((KK)*32)]; \
    asm volatile("s_barrier" ::: "memory"); \
    __builtin_amdgcn_s_setprio(1); \
    _Pragma("unroll") for (int i2 = 0; i2 < 4; ++i2) \
        _Pragma("unroll") for (int j = 0; j < 4; ++j) \
            acc[(IH)*4 + i2][j] = __builtin_amdgcn_mfma_f32_16x16x32_bf16(af[i2], bf[j], acc[(IH)*4 + i2][j], 0, 0, 0); \
    __builtin_amdgcn_s_setprio(0); \
    asm volatile("s_barrier" ::: "memory"); \
} while (0)

#define TILE(KC, CUR, NXT) do { \
    const int sn = ((KC) + 64 < H); \
    const int ln = ((KC) + 128 < H); \
    if (sn) { GLL4(NXT, (KC) + 64); PACKQ(NXT, 0); } \
    MPHASE(CUR, 0, 0); \
    if (sn) { PACKQ(NXT, 1); if (ln) { LOADA(0, (KC) + 128); LOADA(1, (KC) + 128); } } \
    MPHASE(CUR, 1, 0); \
    if (sn) { PACKQ(NXT, 2); } \
    MPHASE(CUR, 0, 1); \
    if (sn) { PACKQ(NXT, 3); if (ln) { LOADA(2, (KC) + 128); LOADA(3, (KC) + 128); } } \
    MPHASE(CUR, 1, 1); \
    if (sn) { \
        if (ln) asm volatile("s_waitcnt vmcnt(8) lgkmcnt(0)\n\ts_barrier" ::: "memory"); \
        else    asm volatile("s_waitcnt vmcnt(0) lgkmcnt(0)\n\ts_barrier" ::: "memory"); \
    } \
} while (0)

    // prologue: stage tile 0 into buf0, prefetch pa <- A(64)
#pragma unroll
    for (int q = 0; q < 4; ++q) LOADA(q, 0);
    GLL4(0, 0);
#pragma unroll
    for (int q = 0; q < 4; ++q) PACKQ(0, q);
#pragma unroll
    for (int q = 0; q < 4; ++q) LOADA(q, 64);
    __syncthreads();

    for (int k0 = 0; k0 < H; k0 += 128) {
        TILE(k0, 0, 1);
        TILE(k0 + 64, 1, 0);
    }

    // epilogue: relu + w2 dot over 4 j-frags x 16 cols -> 16 partials/row
    float part[8][4];
#pragma unroll
    for (int i = 0; i < 8; ++i)
#pragma unroll
        for (int rg = 0; rg < 4; ++rg) part[i][rg] = 0.f;
#pragma unroll
    for (int j = 0; j < 4; ++j) {
        const int col = col0 + wn * 64 + j * 16 + (lane & 15);
        const float b1c = bias1[col];
        const float w2c = w2[col];
#pragma unroll
        for (int i = 0; i < 8; ++i)
#pragma unroll
            for (int rg = 0; rg < 4; ++rg) {
                float hval = acc[i][j][rg] + b1c;
                hval = fmaxf(hval, 0.f);
                part[i][rg] = fmaf(hval, w2c, part[i][rg]);
            }
    }
#pragma unroll
    for (int m = 1; m <= 8; m <<= 1)
#pragma unroll
        for (int i = 0; i < 8; ++i)
#pragma unroll
            for (int rg = 0; rg < 4; ++rg)
                part[i][rg] += __shfl_xor(part[i][rg], m);
    if ((lane & 15) == 0) {
#pragma unroll
        for (int i = 0; i < 8; ++i)
#pragma unroll
            for (int rg = 0; rg < 4; ++rg) {
                const int row = row0 + wm * 128 + i * 16 + (lane >> 4) * 4 + rg;
                xpart[(size_t)row * 16 + nb * 4 + wn] = part[i][rg];
            }
    }
#undef LOADA
#undef PACKQ
#undef GLL4
#undef MPHASE
#undef TILE
}

// ---------------- finish: sum partials, sigmoid, raw score, histogram ----------------
__global__ void k_finishA(const float* __restrict__ xpart, const float* __restrict__ b2,
                          float* __restrict__ fit, float* __restrict__ sraw,
                          int* __restrict__ hist)
{
    const int i = blockIdx.x * 256 + threadIdx.x;
    if (i >= NPOP) return;
    float s = b2[0];
#pragma unroll
    for (int c = 0; c < 16; ++c) s += xpart[(size_t)i * 16 + c];
    sraw[i] = s;
    fit[i] = 1.f / (1.f + expf(-s));
    int b = (int)((s + 4.0f) * 256.0f);
    b = min(max(b, 0), 2047);
    atomicAdd(&hist[b], 1);
}

// ---------------- scan: hist suffix threshold, collect candidates ----------------
__global__ __launch_bounds__(256) void k_scan(const float* __restrict__ sraw,
                                              const int* __restrict__ hist,
                                              int* __restrict__ cand, int* __restrict__ cnt)
{
    __shared__ int ssuf[256];
    __shared__ float sthr;
    const int t = threadIdx.x;
    int local = 0;
#pragma unroll
    for (int j = 0; j < 8; ++j) local += hist[t * 8 + j];
    ssuf[t] = local;
    __syncthreads();
    for (int off = 1; off < 256; off <<= 1) {
        const int v = ssuf[t] + ((t + off < 256) ? ssuf[t + off] : 0);
        __syncthreads();
        ssuf[t] = v;
        __syncthreads();
    }
    if (ssuf[t] >= KSEL && (t == 255 || ssuf[t + 1] < KSEL))
        sthr = -4.0f + (float)(t * 8) * (1.0f / 256.0f) - MARGIN;
    __syncthreads();
    const float thr = sthr;
    const int i = blockIdx.x * 256 + t;
    if (sraw[i] >= thr) {
        const int p = atomicAdd(cnt, 1);
        if (p < CANDCAP) cand[p] = i;
    }
}

// ---------------- exact fp32 rescore: 4 cands/block, 1 wave per cand row ----------------
__global__ __launch_bounds__(256) void k_exact(
    const float* __restrict__ pop, const float* __restrict__ w1,
    const float* __restrict__ b1, const float* __restrict__ w2,
    const int* __restrict__ cand, const int* __restrict__ cnt,
    float* __restrict__ sex16)
{
    const int n = min(*cnt, CANDCAP);
    const int g = blockIdx.y;
    if (g * 4 >= n) return;
    __shared__ float As[4][64];
    __shared__ float Bs[64][64];
    __shared__ int rid[4];
    const int t = threadIdx.x;
    const int cc0 = blockIdx.x * 64;
    if (t < 4) rid[t] = (g * 4 + t < n) ? cand[g * 4 + t] : cand[0];
    __syncthreads();
    const int c  = t & 63;
    const int rw = t >> 6;
    float a0 = 0.f, a1 = 0.f, a2 = 0.f, a3 = 0.f;
    for (int k0 = 0; k0 < H; k0 += 64) {
        __syncthreads();
        As[rw][c] = pop[(size_t)rid[rw] * H + k0 + c];
#pragma unroll
        for (int e = 0; e < 4; ++e) {
            const int kk = (t >> 4) + e * 16;
            *(float4*)&Bs[kk][(t & 15) * 4] =
                *(const float4*)&w1[(size_t)(k0 + kk) * HH + cc0 + (t & 15) * 4];
        }
        __syncthreads();
#pragma unroll
        for (int kk = 0; kk < 64; kk += 4) {
            a0 = fmaf(As[rw][kk + 0], Bs[kk + 0][c], a0);
            a1 = fmaf(As[rw][kk + 1], Bs[kk + 1][c], a1);
            a2 = fmaf(As[rw][kk + 2], Bs[kk + 2][c], a2);
            a3 = fmaf(As[rw][kk + 3], Bs[kk + 3][c], a3);
        }
    }
    const float acc = (a0 + a1) + (a2 + a3);
    float h = fmaxf(acc + b1[cc0 + c], 0.f);
    float p = h * w2[cc0 + c];
#pragma unroll
    for (int s = 32; s >= 1; s >>= 1) p += __shfl_xor(p, s);
    if (c == 0 && g * 4 + rw < n)
        sex16[(size_t)(g * 4 + rw) * 16 + blockIdx.x] = p;
}

// ---------------- final exact top-50: rank-by-counting, single pass ----------------
__global__ __launch_bounds__(1024) void k_final(
    const float* __restrict__ sex16, const int* __restrict__ cand,
    const int* __restrict__ cnt, int* __restrict__ best)
{
    __shared__ unsigned long long skey[1024];
    const int t = threadIdx.x;
    const int n = min(*cnt, CANDCAP);
    unsigned long long key = 0ull;
    if (t < n) {
        float s = 0.f;
#pragma unroll
        for (int c = 0; c < 16; ++c) s += sex16[(size_t)t * 16 + c];
        unsigned u = __float_as_uint(s);
        u = ((int)u < 0) ? ~u : (u | 0x80000000u);
        key = ((unsigned long long)u << 32) | (unsigned)(~(unsigned)cand[t]);
    }
    skey[t] = key;
    __syncthreads();
    if (t < n) {
        int rank = 0;
        for (int j = 0; j < n; ++j) rank += (skey[j] > key) ? 1 : 0;
        if (rank < KSEL) best[rank] = cand[t];
    }
}

// ---------------- mutation partial GEMM (split-K x16, optional row indirection) ----------------
__global__ __launch_bounds__(256) void k_mutp(
    const float* __restrict__ A, const int* __restrict__ bidx,
    const float* __restrict__ W, float* __restrict__ part)
{
    __shared__ float As[KSEL][32];
    __shared__ float Bs[32][64];
    __shared__ int sidx[KSEL];
    const int t = threadIdx.x;
    if (t < KSEL) sidx[t] = bidx ? bidx[t] : t;
    __syncthreads();
    const int col0 = blockIdx.x * 64;
    const int kbeg = blockIdx.y * 128;
    const int c = t & 63;
    const int rg = t >> 6;
    float acc[13];
#pragma unroll
    for (int m = 0; m < 13; ++m) acc[m] = 0.f;

    for (int k0 = kbeg; k0 < kbeg + 128; k0 += 32) {
        __syncthreads();
        for (int e = t; e < KSEL * 8; e += 256) {
            const int r = e >> 3, kc = (e & 7) << 2;
            *(float4*)&As[r][kc] = *(const float4*)&A[(size_t)sidx[r] * H + k0 + kc];
        }
        for (int e = t; e < 32 * 16; e += 256) {
            const int kk = e >> 4, cc = (e & 15) << 2;
            *(float4*)&Bs[kk][cc] = *(const float4*)&W[(size_t)(k0 + kk) * H + col0 + cc];
        }
        __syncthreads();
#pragma unroll
        for (int k4 = 0; k4 < 8; ++k4) {
            const float bv0 = Bs[k4 * 4 + 0][c];
            const float bv1 = Bs[k4 * 4 + 1][c];
            const float bv2 = Bs[k4 * 4 + 2][c];
            const float bv3 = Bs[k4 * 4 + 3][c];
#pragma unroll
            for (int m = 0; m < 13; ++m) {
                const int r = rg + m * 4;
                if (r < KSEL) {
                    const float4 av = *(const float4*)&As[r][k4 * 4];
                    acc[m] = fmaf(av.x, bv0, acc[m]);
                    acc[m] = fmaf(av.y, bv1, acc[m]);
                    acc[m] = fmaf(av.z, bv2, acc[m]);
                    acc[m] = fmaf(av.w, bv3, acc[m]);
                }
            }
        }
    }
#pragma unroll
    for (int m = 0; m < 13; ++m) {
        const int r = rg + m * 4;
        if (r < KSEL)
            part[((size_t)blockIdx.y * KSEL + r) * H + col0 + c] = acc[m];
    }
}

__global__ void k_mut1c(const float* __restrict__ part, const float* __restrict__ b,
                        float* __restrict__ mid)
{
    const int i = blockIdx.x * 256 + threadIdx.x;
    if (i >= KSEL * H) return;
    const int c = i & 2047;
    float s = 0.f;
#pragma unroll
    for (int p = 0; p < 16; ++p) s += part[i + (size_t)p * KSEL * H];
    const float v = s + b[c];
    mid[i] = 0.5f * v * (1.f + erff(v * 0.70710678118654752f));
}

__global__ void k_mut2c(const float* __restrict__ part, const float* __restrict__ b,
                        const float* __restrict__ pop, const int* __restrict__ best,
                        const void* __restrict__ mask,
                        const int* __restrict__ mflag, float* __restrict__ out)
{
    const int i = blockIdx.x * 256 + threadIdx.x;
    if (i >= KSEL * H) return;
    const int c = i & 2047;
    const int r = i >> 11;
    float s = 0.f;
#pragma unroll
    for (int p = 0; p < 16; ++p) s += part[i + (size_t)p * KSEL * H];
    const float v = s + b[c];
    const int mf = *mflag;
    bool mv;
    if (mf == 2)      mv = ((const float*)mask)[i] != 0.f;
    else if (mf == 1) mv = ((const unsigned char*)mask)[i] != 0;
    else              mv = ((const int*)mask)[i] != 0;
    out[i] = mv ? pop[(size_t)best[r] * H + c] : v;
}

// ================= fallback (round-1 proven) path =================
__global__ void k_maskdetect(const unsigned int* __restrict__ m, int* __restrict__ flag,
                             int* __restrict__ cnt, int* __restrict__ hist) {
    __shared__ int sfloat, sbyte;
    if (threadIdx.x == 0) { sfloat = 0; sbyte = 0; *cnt = 0; }
    for (int i = threadIdx.x; i < 2048; i += 256) hist[i] = 0;
    __syncthreads();
    for (int i = threadIdx.x; i < 25600; i += 256) {
        unsigned int v = m[i];
        if (v == 0x3F800000u) sfloat = 1;
        else if (v & 0xFFFFFF00u) sbyte = 1;
    }
    __syncthreads();
    if (threadIdx.x == 0) *flag = sfloat ? 2 : (sbyte ? 1 : 0);
}

__global__ __launch_bounds__(256) void k_fit_gemm(
    const float* __restrict__ pop, const float* __restrict__ w1,
    const float* __restrict__ bias1, const float* __restrict__ w2,
    float* __restrict__ xpart)
{
    __shared__ float As[16][128];
    __shared__ float Bs[16][128];
    const int nb   = blockIdx.x;
    const int row0 = blockIdx.y * 128;
    const int col0 = nb * 128;
    const int t  = threadIdx.x;
    const int tx = t & 15;
    const int ty = t >> 4;
    float acc[8][8];
#pragma unroll
    for (int i = 0; i < 8; ++i)
#pragma unroll
        for (int j = 0; j < 8; ++j) acc[i][j] = 0.f;
    const int lr = t >> 1;
    const int lk = (t & 1) * 8;
    const int bk = t >> 4;
    const int bc = (t & 15) * 8;
    for (int k0 = 0; k0 < H; k0 += 16) {
        const float4 a0 = *(const float4*)(pop + (size_t)(row0 + lr) * H + k0 + lk);
        const float4 a1 = *(const float4*)(pop + (size_t)(row0 + lr) * H + k0 + lk + 4);
        const float4 c0 = *(const float4*)(w1 + (size_t)(k0 + bk) * HH + col0 + bc);
        const float4 c1 = *(const float4*)(w1 + (size_t)(k0 + bk) * HH + col0 + bc + 4);
        __syncthreads();
        As[lk + 0][lr] = a0.x; As[lk + 1][lr] = a0.y; As[lk + 2][lr] = a0.z; As[lk + 3][lr] = a0.w;
        As[lk + 4][lr] = a1.x; As[lk + 5][lr] = a1.y; As[lk + 6][lr] = a1.z; As[lk + 7][lr] = a1.w;
        *(float4*)&Bs[bk][bc]     = c0;
        *(float4*)&Bs[bk][bc + 4] = c1;
        __syncthreads();
#pragma unroll
        for (int kk = 0; kk < 16; ++kk) {
            const float4 ra0 = *(const float4*)&As[kk][ty * 8];
            const float4 ra1 = *(const float4*)&As[kk][ty * 8 + 4];
            const float4 rb0 = *(const float4*)&Bs[kk][tx * 8];
            const float4 rb1 = *(const float4*)&Bs[kk][tx * 8 + 4];
            const float av[8] = {ra0.x, ra0.y, ra0.z, ra0.w, ra1.x, ra1.y, ra1.z, ra1.w};
            const float bv[8] = {rb0.x, rb0.y, rb0.z, rb0.w, rb1.x, rb1.y, rb1.z, rb1.w};
#pragma unroll
            for (int i = 0; i < 8; ++i)
#pragma unroll
                for (int j = 0; j < 8; ++j)
                    acc[i][j] = fmaf(av[i], bv[j], acc[i][j]);
        }
    }
    float part[8];
#pragma unroll
    for (int i = 0; i < 8; ++i) part[i] = 0.f;
#pragma unroll
    for (int j = 0; j < 8; ++j) {
        const int c = col0 + tx * 8 + j;
        const float bb = bias1[c];
        const float ww = w2[c];
#pragma unroll
        for (int i = 0; i < 8; ++i) {
            float hh = acc[i][j] + bb;
            hh = fmaxf(hh, 0.f);
            part[i] = fmaf(hh, ww, part[i]);
        }
    }
#pragma unroll
    for (int m = 1; m <= 8; m <<= 1)
#pragma unroll
        for (int i = 0; i < 8; ++i) part[i] += __shfl_xor(part[i], m);
    if (tx == 0) {
#pragma unroll
        for (int i = 0; i < 8; ++i)
            xpart[(size_t)(row0 + ty * 8 + i) * 8 + nb] = part[i];
    }
}

__global__ void k_fit_finish8(const float* __restrict__ xpart,
                              const float* __restrict__ b2, float* __restrict__ fit)
{
    const int i = blockIdx.x * 256 + threadIdx.x;
    if (i >= NPOP) return;
    float s = b2[0];
#pragma unroll
    for (int nb = 0; nb < 8; ++nb) s += xpart[(size_t)i * 8 + nb];
    fit[i] = 1.f / (1.f + expf(-s));
}

__global__ __launch_bounds__(1024) void k_topk3(const float* __restrict__ fit,
                                                int* __restrict__ best)
{
    __shared__ unsigned long long skey[1024];
    __shared__ unsigned long long wred[16];
    __shared__ unsigned int taken[NPOP / 32];
    __shared__ int brd;
    const int t = threadIdx.x;
    for (int i = t; i < NPOP / 32; i += 1024) taken[i] = 0u;
    unsigned long long k = 0ull;
#pragma unroll 4
    for (int i = 0; i < 64; ++i) {
        const int idx = t + (i << 10);
        const unsigned fv = __float_as_uint(fit[idx]);
        const unsigned long long key = ((unsigned long long)fv << 32) | (unsigned)(~(unsigned)idx);
        if (key > k) k = key;
    }
    skey[t] = k;
    __syncthreads();
    for (int r = 0; r < KSEL; ++r) {
        unsigned long long v = skey[t];
#pragma unroll
        for (int m = 32; m >= 1; m >>= 1) {
            const unsigned long long o = __shfl_xor(v, m);
            if (o > v) v = o;
        }
        if ((t & 63) == 0) wred[t >> 6] = v;
        __syncthreads();
        if (t == 0) {
            unsigned long long b = wred[0];
#pragma unroll
            for (int w = 1; w < 16; ++w) if (wred[w] > b) b = wred[w];
            const int idx = (int)(~(unsigned)(b & 0xFFFFFFFFull));
            best[r] = idx;
            taken[idx >> 5] |= (1u << (idx & 31));
            brd = idx;
        }
        __syncthreads();
        if (r + 1 < KSEL) {
            const int s = brd & 1023;
            if (t < 64) {
                const int e = s + (t << 10);
                unsigned long long k2 = 0ull;
                if (!(taken[e >> 5] & (1u << (e & 31)))) {
                    const unsigned fv = __float_as_uint(fit[e]);
                    k2 = ((unsigned long long)fv << 32) | (unsigned)(~(unsigned)e);
                }
#pragma unroll
                for (int m = 32; m >= 1; m >>= 1) {
                    const unsigned long long o = __shfl_xor(k2, m);
                    if (o > k2) k2 = o;
                }
                if (t == 0) skey[s] = k2;
            }
            __syncthreads();
        }
    }
}

__global__ __launch_bounds__(256) void k_mut1(
    const float* __restrict__ pop, const int* __restrict__ best,
    const float* __restrict__ w, const float* __restrict__ b, float* __restrict__ mid)
{
    __shared__ float As[KSEL][32];
    __shared__ float Bs[32][64];
    __shared__ int sidx[KSEL];
    const int t = threadIdx.x;
    if (t < KSEL) sidx[t] = best[t];
    __syncthreads();
    const int col0 = blockIdx.x * 64;
    const int c  = t & 63;
    const int rg = t >> 6;
    float acc[13];
#pragma unroll
    for (int m = 0; m < 13; ++m) acc[m] = 0.f;
    for (int k0 = 0; k0 < H; k0 += 32) {
        __syncthreads();
        for (int e = t; e < KSEL * 32; e += 256) {
            const int r = e >> 5, kk = e & 31;
            As[r][kk] = pop[(size_t)sidx[r] * H + k0 + kk];
        }
        for (int e = t; e < 32 * 64; e += 256) {
            const int kk = e >> 6, cc = e & 63;
            Bs[kk][cc] = w[(size_t)(k0 + kk) * H + col0 + cc];
        }
        __syncthreads();
#pragma unroll
        for (int k4 = 0; k4 < 8; ++k4) {
            const float bv0 = Bs[k4 * 4 + 0][c];
            const float bv1 = Bs[k4 * 4 + 1][c];
            const float bv2 = Bs[k4 * 4 + 2][c];
            const float bv3 = Bs[k4 * 4 + 3][c];
#pragma unroll
            for (int m = 0; m < 13; ++m) {
                const int r = rg + m * 4;
                if (r < KSEL) {
                    const float4 av = *(const float4*)&As[r][k4 * 4];
                    acc[m] = fmaf(av.x, bv0, acc[m]);
                    acc[m] = fmaf(av.y, bv1, acc[m]);
                    acc[m] = fmaf(av.z, bv2, acc[m]);
                    acc[m] = fmaf(av.w, bv3, acc[m]);
                }
            }
        }
    }
#pragma unroll
    for (int m = 0; m < 13; ++m) {
        const int r = rg + m * 4;
        if (r < KSEL) {
            const int col = col0 + c;
            const float v = acc[m] + b[col];
            mid[(size_t)r * H + col] = 0.5f * v * (1.f + erff(v * 0.70710678118654752f));
        }
    }
}

__global__ __launch_bounds__(256) void k_mut2(
    const float* __restrict__ mid, const float* __restrict__ w,
    const float* __restrict__ b, const float* __restrict__ pop,
    const int* __restrict__ best, const void* __restrict__ mask,
    const int* __restrict__ mflag, float* __restrict__ out)
{
    __shared__ float As[KSEL][32];
    __shared__ float Bs[32][64];
    __shared__ int sidx[KSEL];
    const int t = threadIdx.x;
    if (t < KSEL) sidx[t] = best[t];
    __syncthreads();
    const int col0 = blockIdx.x * 64;
    const int c  = t & 63;
    const int rg = t >> 6;
    const int mf = *mflag;
    float acc[13];
#pragma unroll
    for (int m = 0; m < 13; ++m) acc[m] = 0.f;
    for (int k0 = 0; k0 < H; k0 += 32) {
        __syncthreads();
        for (int e = t; e < KSEL * 32; e += 256) {
            const int r = e >> 5, kk = e & 31;
            As[r][kk] = mid[(size_t)r * H + k0 + kk];
        }
        for (int e = t; e < 32 * 64; e += 256) {
            const int kk = e >> 6, cc = e & 63;
            Bs[kk][cc] = w[(size_t)(k0 + kk) * H + col0 + cc];
        }
        __syncthreads();
#pragma unroll
        for (int k4 = 0; k4 < 8; ++k4) {
            const float bv0 = Bs[k4 * 4 + 0][c];
            const float bv1 = Bs[k4 * 4 + 1][c];
            const float bv2 = Bs[k4 * 4 + 2][c];
            const float bv3 = Bs[k4 * 4 + 3][c];
#pragma unroll
            for (int m = 0; m < 13; ++m) {
                const int r = rg + m * 4;
                if (r < KSEL) {
                    const float4 av = *(const float4*)&As[r][k4 * 4];
                    acc[m] = fmaf(av.x, bv0, acc[m]);
                    acc[m] = fmaf(av.y, bv1, acc[m]);
                    acc[m] = fmaf(av.z, bv2, acc[m]);
                    acc[m] = fmaf(av.w, bv3, acc[m]);
                }
            }
        }
    }
#pragma unroll
    for (int m = 0; m < 13; ++m) {
        const int r = rg + m * 4;
        if (r < KSEL) {
            const int col = col0 + c;
            const size_t mi = (size_t)r * H + col;
            const float v = acc[m] + b[col];
            bool mv;
            if (mf == 2)      mv = ((const float*)mask)[mi] != 0.f;
            else if (mf == 1) mv = ((const unsigned char*)mask)[mi] != 0;
            else              mv = ((const int*)mask)[mi] != 0;
            out[mi] = mv ? pop[(size_t)sidx[r] * H + col] : v;
        }
    }
}

// ================= launcher =================
extern "C" void kernel_launch(void* const* d_in, const int* in_sizes, int n_in,
                              void* d_out, int out_size, void* d_ws, size_t ws_size,
                              hipStream_t stream) {
    const float* pop = (const float*)d_in[0];
    const float* sw1 = (const float*)d_in[1];
    const float* sb1 = (const float*)d_in[2];
    const float* sw2 = (const float*)d_in[3];
    const float* sb2 = (const float*)d_in[4];
    const float* mw1 = (const float*)d_in[5];
    const float* mb1 = (const float*)d_in[6];
    const float* mw2 = (const float*)d_in[7];
    const float* mb2 = (const float*)d_in[8];
    const void*  mask = d_in[9];

    float* out_off = (float*)d_out;
    float* out_fit = (float*)d_out + (size_t)KSEL * H;

    char* ws = (char*)d_ws;

    // fast-path ws layout (bytes)
    const size_t W1T_OFF   = 0;            // 4,194,304
    const size_t XPART_OFF = 4194304;      // 65536*16*4 = 4,194,304
    const size_t SRAW_OFF  = 8388608;      // 262,144
    const size_t HIST_OFF  = 8650752;      // 8,192
    const size_t PPART_OFF = 8658944;      // 16*50*2048*4 = 6,553,600
    const size_t MID_OFF   = 15212544;     // 409,600
    const size_t CAND_OFF  = 15622144;     // 4,096
    const size_t SEX_OFF   = 15626240;     // 65,536
    const size_t BEST_OFF  = 15691776;     // 256
    const size_t MFLAG_OFF = 15692032;     // 128
    const size_t CNT_OFF   = 15692160;     // 128
    const size_t NEED      = 15692288;

    if (ws_size >= NEED) {
        unsigned short* w1t  = (unsigned short*)(ws + W1T_OFF);
        float* xpart = (float*)(ws + XPART_OFF);
        float* sraw  = (float*)(ws + SRAW_OFF);
        int*   hist  = (int*)(ws + HIST_OFF);
        float* ppart = (float*)(ws + PPART_OFF);
        float* mid   = (float*)(ws + MID_OFF);
        int*   cand  = (int*)(ws + CAND_OFF);
        float* sex16 = (float*)(ws + SEX_OFF);
        int*   best  = (int*)(ws + BEST_OFF);
        int*   mflag = (int*)(ws + MFLAG_OFF);
        int*   cnt   = (int*)(ws + CNT_OFF);

        hipLaunchKernelGGL(k_w1split, dim3(16, 32), dim3(256), 0, stream,
                           sw1, w1t, (const unsigned int*)mask, mflag, cnt, hist);
        hipLaunchKernelGGL(k_fit_8ph, dim3(1024), dim3(512), 0, stream,
                           pop, w1t, sb1, sw2, xpart);
        hipLaunchKernelGGL(k_finishA, dim3(NPOP / 256), dim3(256), 0, stream,
                           xpart, sb2, out_fit, sraw, hist);
        hipLaunchKernelGGL(k_scan, dim3(NPOP / 256), dim3(256), 0, stream,
                           sraw, hist, cand, cnt);
        hipLaunchKernelGGL(k_exact, dim3(16, 256), dim3(256), 0, stream,
                           pop, sw1, sb1, sw2, cand, cnt, sex16);
        hipLaunchKernelGGL(k_final, dim3(1), dim3(1024), 0, stream,
                           sex16, cand, cnt, best);
        hipLaunchKernelGGL(k_mutp, dim3(32, 16), dim3(256), 0, stream,
                           pop, best, mw1, ppart);
        hipLaunchKernelGGL(k_mut1c, dim3(KSEL * H / 256), dim3(256), 0, stream,
                           ppart, mb1, mid);
        hipLaunchKernelGGL(k_mutp, dim3(32, 16), dim3(256), 0, stream,
                           mid, (const int*)nullptr, mw2, ppart);
        hipLaunchKernelGGL(k_mut2c, dim3(KSEL * H / 256), dim3(256), 0, stream,
                           ppart, mb2, pop, best, mask, mflag, out_off);
    } else {
        // fallback: round-1 proven path (exact fp32 fitness)
        float* xpart = (float*)ws;
        int*   best  = (int*)(ws + (size_t)NPOP * 8 * 4);
        int*   mflag = (int*)(ws + (size_t)NPOP * 8 * 4 + 256);
        int*   cnt   = (int*)(ws + (size_t)NPOP * 8 * 4 + 384);
        int*   hist  = (int*)(ws + (size_t)NPOP * 8 * 4 + 512);
        float* mid   = (float*)(ws + (size_t)NPOP * 8 * 4 + 8704);

        hipLaunchKernelGGL(k_maskdetect, dim3(1), dim3(256), 0, stream,
                           (const unsigned int*)mask, mflag, cnt, hist);
        hipLaunchKernelGGL(k_fit_gemm, dim3(8, 512), dim3(256), 0, stream,
                           pop, sw1, sb1, sw2, xpart);
        hipLaunchKernelGGL(k_fit_finish8, dim3(NPOP / 256), dim3(256), 0, stream,
                           xpart, sb2, out_fit);
        hipLaunchKernelGGL(k_topk3, dim3(1), dim3(1024), 0, stream, out_fit, best);
        hipLaunchKernelGGL(k_mut1, dim3(H / 64), dim3(256), 0, stream,
                           pop, best, mw1, mb1, mid);
        hipLaunchKernelGGL(k_mut2, dim3(H / 64), dim3(256), 0, stream,
                           mid, mw2, mb2, pop, best, mask, mflag, out_off);
    }
}